// Round 3
// baseline (460.340 us; speedup 1.0000x reference)
//
#include <hip/hip_runtime.h>
#include <hip/hip_bf16.h>

#define NUM_CLASS 21
#define IGNORE_L 255
#define EPSF 1e-6f
// Problem dims (fixed by setup_inputs): B=8, D=512, H=W=128 -> HW=16384
#define BATCH 8
#define DCH 512
#define HW 16384
#define NROWS (BATCH * DCH)   // 4096 scatter blocks

__device__ __forceinline__ float waveReduce(float v) {
    #pragma unroll
    for (int m = 1; m < 64; m <<= 1) v += __shfl_xor(v, m, 64);
    return v;
}

// ---------------------------------------------------------------------------
// Kernel 1: per-(b,d) row segmented class sums + per-block sum of squares.
// One block per row. Anti-channel-camping: iteration order rotated by
// (row & 7) so co-resident blocks touch different 4-8KB regions at any
// instant (64KB row stride aliases channel-select bits otherwise).
// ---------------------------------------------------------------------------
__global__ __launch_bounds__(256) void car_scatter_kernel(
    const float* __restrict__ features, const int* __restrict__ label,
    float* __restrict__ class_sum, float* __restrict__ ss_parts)
{
    __shared__ float sm[NUM_CLASS * 64];
    __shared__ float red[4];
    const int t = threadIdx.x;
    const int lane = t & 63;
    const int wave = t >> 6;
    const int row = blockIdx.x;      // b*512 + d
    const int b = row >> 9;
    const int d = row & 511;

    for (int i = t; i < NUM_CLASS * 64; i += 256) sm[i] = 0.0f;
    __syncthreads();

    const float4* __restrict__ frow = (const float4*)(features + (size_t)row * HW);
    const int4*  __restrict__ lrow = (const int4*)(label + (size_t)b * HW);

    const int i0 = row & 7;
    float ss = 0.0f;
    #pragma unroll
    for (int ii = 0; ii < 8; ++ii) {
        const int i = (ii + i0) & 7;
        const int base = i * 512 + t;
        float4 f0 = frow[base];
        float4 f1 = frow[base + 256];
        int4   l0 = lrow[base];
        int4   l1 = lrow[base + 256];

        if (l0.x != IGNORE_L) ss += f0.x * f0.x;
        if ((unsigned)l0.x < NUM_CLASS) atomicAdd(&sm[l0.x * 64 + lane], f0.x);
        if (l0.y != IGNORE_L) ss += f0.y * f0.y;
        if ((unsigned)l0.y < NUM_CLASS) atomicAdd(&sm[l0.y * 64 + lane], f0.y);
        if (l0.z != IGNORE_L) ss += f0.z * f0.z;
        if ((unsigned)l0.z < NUM_CLASS) atomicAdd(&sm[l0.z * 64 + lane], f0.z);
        if (l0.w != IGNORE_L) ss += f0.w * f0.w;
        if ((unsigned)l0.w < NUM_CLASS) atomicAdd(&sm[l0.w * 64 + lane], f0.w);

        if (l1.x != IGNORE_L) ss += f1.x * f1.x;
        if ((unsigned)l1.x < NUM_CLASS) atomicAdd(&sm[l1.x * 64 + lane], f1.x);
        if (l1.y != IGNORE_L) ss += f1.y * f1.y;
        if ((unsigned)l1.y < NUM_CLASS) atomicAdd(&sm[l1.y * 64 + lane], f1.y);
        if (l1.z != IGNORE_L) ss += f1.z * f1.z;
        if ((unsigned)l1.z < NUM_CLASS) atomicAdd(&sm[l1.z * 64 + lane], f1.z);
        if (l1.w != IGNORE_L) ss += f1.w * f1.w;
        if ((unsigned)l1.w < NUM_CLASS) atomicAdd(&sm[l1.w * 64 + lane], f1.w);
    }
    __syncthreads();

    float* __restrict__ out_row = class_sum + (size_t)b * NUM_CLASS * DCH + d;
    for (int c = wave; c < NUM_CLASS; c += 4) {
        float v = sm[c * 64 + lane];
        v = waveReduce(v);
        if (lane == 0) out_row[(size_t)c * DCH] = v;
    }

    ss = waveReduce(ss);
    if (lane == 0) red[wave] = ss;
    __syncthreads();
    if (t == 0) ss_parts[row] = red[0] + red[1] + red[2] + red[3];
}

// ---------------------------------------------------------------------------
// Probe (bisect instrumentation): identical loads + ss, NO LDS atomics.
// Separate dispatch so rocprof attributes it separately.
// ---------------------------------------------------------------------------
__global__ __launch_bounds__(256) void car_probe_kernel(
    const float* __restrict__ features, const int* __restrict__ label,
    float* __restrict__ probe_parts)
{
    __shared__ float red[4];
    const int t = threadIdx.x;
    const int lane = t & 63;
    const int wave = t >> 6;
    const int row = blockIdx.x;
    const int b = row >> 9;

    const float4* __restrict__ frow = (const float4*)(features + (size_t)row * HW);
    const int4*  __restrict__ lrow = (const int4*)(label + (size_t)b * HW);

    const int i0 = row & 7;
    float ss = 0.0f;
    #pragma unroll
    for (int ii = 0; ii < 8; ++ii) {
        const int i = (ii + i0) & 7;
        const int base = i * 512 + t;
        float4 f0 = frow[base];
        float4 f1 = frow[base + 256];
        int4   l0 = lrow[base];
        int4   l1 = lrow[base + 256];
        if (l0.x != IGNORE_L) ss += f0.x * f0.x;
        if (l0.y != IGNORE_L) ss += f0.y * f0.y;
        if (l0.z != IGNORE_L) ss += f0.z * f0.z;
        if (l0.w != IGNORE_L) ss += f0.w * f0.w;
        if (l1.x != IGNORE_L) ss += f1.x * f1.x;
        if (l1.y != IGNORE_L) ss += f1.y * f1.y;
        if (l1.z != IGNORE_L) ss += f1.z * f1.z;
        if (l1.w != IGNORE_L) ss += f1.w * f1.w;
    }

    ss = waveReduce(ss);
    if (lane == 0) red[wave] = ss;
    __syncthreads();
    if (t == 0) probe_parts[row] = red[0] + red[1] + red[2] + red[3];
}

// ---------------------------------------------------------------------------
// Kernel 2: per-batch class histogram (counts) + per-batch valid count.
// ---------------------------------------------------------------------------
__global__ __launch_bounds__(256) void car_counts_kernel(
    const int* __restrict__ label, float* __restrict__ counts,
    float* __restrict__ total_parts)
{
    __shared__ float sm[NUM_CLASS * 64];
    __shared__ float red[4];
    const int t = threadIdx.x;
    const int lane = t & 63;
    const int wave = t >> 6;
    const int b = blockIdx.x;

    for (int i = t; i < NUM_CLASS * 64; i += 256) sm[i] = 0.0f;
    __syncthreads();

    const int4* __restrict__ lrow = (const int4*)(label + (size_t)b * HW);
    float tv = 0.0f;
    #pragma unroll 4
    for (int i = 0; i < HW / (256 * 4); ++i) {
        int4 l = lrow[i * 256 + t];
        if (l.x != IGNORE_L) tv += 1.0f;
        if ((unsigned)l.x < NUM_CLASS) atomicAdd(&sm[l.x * 64 + lane], 1.0f);
        if (l.y != IGNORE_L) tv += 1.0f;
        if ((unsigned)l.y < NUM_CLASS) atomicAdd(&sm[l.y * 64 + lane], 1.0f);
        if (l.z != IGNORE_L) tv += 1.0f;
        if ((unsigned)l.z < NUM_CLASS) atomicAdd(&sm[l.z * 64 + lane], 1.0f);
        if (l.w != IGNORE_L) tv += 1.0f;
        if ((unsigned)l.w < NUM_CLASS) atomicAdd(&sm[l.w * 64 + lane], 1.0f);
    }
    __syncthreads();

    for (int c = wave; c < NUM_CLASS; c += 4) {
        float v = sm[c * 64 + lane];
        v = waveReduce(v);
        if (lane == 0) counts[b * NUM_CLASS + c] = v;
    }

    tv = waveReduce(tv);
    if (lane == 0) red[wave] = tv;
    __syncthreads();
    if (t == 0) total_parts[b] = red[0] + red[1] + red[2] + red[3];
}

// ---------------------------------------------------------------------------
// Kernel 3: finalize (1 block, 512 threads).
// ---------------------------------------------------------------------------
__global__ __launch_bounds__(512) void car_finalize_kernel(
    const float* __restrict__ class_sum, const float* __restrict__ counts,
    const float* __restrict__ ss_parts, const float* __restrict__ total_parts,
    float* __restrict__ out)
{
    __shared__ float cm[NUM_CLASS * DCH];
    __shared__ float norms[NUM_CLASS];
    __shared__ float redC[8];
    __shared__ float redS[8];
    __shared__ float redB[8];
    const int t = threadIdx.x;
    const int lane = t & 63;
    const int wave = t >> 6;

    float ssp = 0.0f;
    #pragma unroll
    for (int i = 0; i < NROWS / 512; ++i) ssp += ss_parts[i * 512 + t];

    float corr = 0.0f;
    for (int p = t; p < NUM_CLASS * DCH; p += 512) {
        const int c = p >> 9;
        float s = 0.0f;
        #pragma unroll
        for (int b = 0; b < BATCH; ++b) {
            float S = class_sum[(size_t)b * NUM_CLASS * DCH + p];
            float n = counts[b * NUM_CLASS + c];
            float cen = S / (n + EPSF);
            corr += cen * (n * cen - 2.0f * S);
            s += cen;
        }
        cm[p] = s * (1.0f / BATCH);
    }
    corr = waveReduce(corr);
    ssp  = waveReduce(ssp);
    if (lane == 0) { redC[wave] = corr; redS[wave] = ssp; }
    __syncthreads();

    for (int c = wave; c < NUM_CLASS; c += 8) {
        float s = 0.0f;
        #pragma unroll
        for (int k = 0; k < DCH / 64; ++k) {
            float v = cm[c * DCH + k * 64 + lane];
            s += v * v;
        }
        s = waveReduce(s);
        if (lane == 0) norms[c] = fmaxf(sqrtf(s), 1e-12f);
    }
    __syncthreads();

    float interAcc = 0.0f;
    for (int p = wave; p < NUM_CLASS * NUM_CLASS; p += 8) {
        const int c1 = p / NUM_CLASS;
        const int c2 = p % NUM_CLASS;
        if (c1 == c2) continue;
        float s = 0.0f;
        #pragma unroll
        for (int k = 0; k < DCH / 64; ++k)
            s += cm[c1 * DCH + k * 64 + lane] * cm[c2 * DCH + k * 64 + lane];
        s = waveReduce(s);
        if (lane == 0) {
            float sim = s / (norms[c1] * norms[c2]);
            interAcc += fmaxf(sim - 0.5f, 0.0f);
        }
    }
    if (lane == 0) redB[wave] = interAcc;
    __syncthreads();

    if (t == 0) {
        float corrT = 0.0f, interT = 0.0f, ssT = 0.0f, tot = 0.0f;
        #pragma unroll
        for (int w = 0; w < 8; ++w) { corrT += redC[w]; interT += redB[w]; ssT += redS[w]; }
        #pragma unroll
        for (int b = 0; b < BATCH; ++b) tot += total_parts[b];
        out[0] = (ssT + corrT) / (tot + EPSF);
        out[1] = interT / ((float)NUM_CLASS + EPSF);
    }
}

extern "C" void kernel_launch(void* const* d_in, const int* in_sizes, int n_in,
                              void* d_out, int out_size, void* d_ws, size_t ws_size,
                              hipStream_t stream) {
    const float* features = (const float*)d_in[0];
    const int*   label    = (const int*)d_in[1];
    float* out = (float*)d_out;

    // ws layout (floats):
    //   [0 .. 4096)          ss_parts
    //   [4096 .. 4104)       total_parts
    //   [4104 .. 4272)       counts (8*21)
    //   [4352 .. 90368)      class_sum[8][21][512]
    //   [90368 .. 94464)     probe_parts (diagnostic only)
    float* ws          = (float*)d_ws;
    float* ss_parts    = ws + 0;
    float* total_parts = ws + 4096;
    float* counts      = ws + 4104;
    float* class_sum   = ws + 4352;
    float* probe_parts = ws + 90368;

    // Diagnostic bisect dispatch (separate rocprof row); skipped if ws small.
    if (ws_size >= (size_t)(90368 + NROWS) * sizeof(float)) {
        car_probe_kernel<<<NROWS, 256, 0, stream>>>(features, label, probe_parts);
    }
    car_counts_kernel<<<BATCH, 256, 0, stream>>>(label, counts, total_parts);
    car_scatter_kernel<<<NROWS, 256, 0, stream>>>(features, label, class_sum, ss_parts);
    car_finalize_kernel<<<1, 512, 0, stream>>>(class_sum, counts, ss_parts, total_parts, out);
}

// Round 4
// 106.538 us; speedup vs baseline: 4.3209x; 4.3209x over previous
//
#include <hip/hip_runtime.h>
#include <hip/hip_bf16.h>

#define NUM_CLASS 21
#define IGNORE_L 255
#define EPSF 1e-6f
// Problem dims (fixed by setup_inputs): B=8, D=512, H=W=128 -> HW=16384
#define BATCH 8
#define DCH 512
#define HW 16384
#define NROWS (BATCH * DCH)   // 4096 scatter blocks

__device__ __forceinline__ float waveReduce(float v) {
    #pragma unroll
    for (int m = 1; m < 64; m <<= 1) v += __shfl_xor(v, m, 64);
    return v;
}

// ---------------------------------------------------------------------------
// Kernel 1: per-(b,d) row segmented class sums + per-block sum of squares.
// One block per row (b*512+d).
// NO LDS atomics: measured ds_add_f32 throughput is ~3.2 cyc/LANE (lane-serial
// RMW in the DS unit) -> 350us. Instead each WAVE gets a private accumulator
// copy sm[wave][class][lane]; plain ds_read+add+ds_write runs wave-wide.
// In-order DS execution per wave makes same-address RMW sequences safe.
// Slot bank = lane%32 -> 2-way aliasing (free).
// ---------------------------------------------------------------------------
__global__ __launch_bounds__(256) void car_scatter_kernel(
    const float* __restrict__ features, const int* __restrict__ label,
    float* __restrict__ class_sum, float* __restrict__ ss_parts)
{
    __shared__ float sm[4][NUM_CLASS * 64];
    __shared__ float red[4];
    const int t = threadIdx.x;
    const int lane = t & 63;
    const int wave = t >> 6;
    const int row = blockIdx.x;      // b*512 + d
    const int b = row >> 9;
    const int d = row & 511;

    float* __restrict__ smw = &sm[wave][0];
    for (int i = lane; i < NUM_CLASS * 64; i += 64) smw[i] = 0.0f;
    __syncthreads();

    const float4* __restrict__ frow = (const float4*)(features + (size_t)row * HW);
    const int4*  __restrict__ lrow = (const int4*)(label + (size_t)b * HW);

    float ss = 0.0f;
    #pragma unroll 2
    for (int i = 0; i < HW / (256 * 4); ++i) {
        float4 f = frow[i * 256 + t];
        int4   l = lrow[i * 256 + t];

        if (l.x != IGNORE_L) ss += f.x * f.x;
        if ((unsigned)l.x < NUM_CLASS) { float v = smw[l.x * 64 + lane]; smw[l.x * 64 + lane] = v + f.x; }
        if (l.y != IGNORE_L) ss += f.y * f.y;
        if ((unsigned)l.y < NUM_CLASS) { float v = smw[l.y * 64 + lane]; smw[l.y * 64 + lane] = v + f.y; }
        if (l.z != IGNORE_L) ss += f.z * f.z;
        if ((unsigned)l.z < NUM_CLASS) { float v = smw[l.z * 64 + lane]; smw[l.z * 64 + lane] = v + f.z; }
        if (l.w != IGNORE_L) ss += f.w * f.w;
        if ((unsigned)l.w < NUM_CLASS) { float v = smw[l.w * 64 + lane]; smw[l.w * 64 + lane] = v + f.w; }
    }
    __syncthreads();

    // Merge the 4 wave-copies and reduce 64 lane-slots per class.
    float* __restrict__ out_row = class_sum + (size_t)b * NUM_CLASS * DCH + d;
    for (int c = wave; c < NUM_CLASS; c += 4) {
        const int idx = c * 64 + lane;
        float v = sm[0][idx] + sm[1][idx] + sm[2][idx] + sm[3][idx];
        v = waveReduce(v);
        if (lane == 0) out_row[(size_t)c * DCH] = v;
    }

    ss = waveReduce(ss);
    if (lane == 0) red[wave] = ss;
    __syncthreads();
    if (t == 0) ss_parts[row] = red[0] + red[1] + red[2] + red[3];
}

// ---------------------------------------------------------------------------
// Kernel 2: per-batch class histogram (counts) + per-batch valid count.
// Same no-atomic per-wave-private scheme.
// ---------------------------------------------------------------------------
__global__ __launch_bounds__(256) void car_counts_kernel(
    const int* __restrict__ label, float* __restrict__ counts,
    float* __restrict__ total_parts)
{
    __shared__ float sm[4][NUM_CLASS * 64];
    __shared__ float red[4];
    const int t = threadIdx.x;
    const int lane = t & 63;
    const int wave = t >> 6;
    const int b = blockIdx.x;

    float* __restrict__ smw = &sm[wave][0];
    for (int i = lane; i < NUM_CLASS * 64; i += 64) smw[i] = 0.0f;
    __syncthreads();

    const int4* __restrict__ lrow = (const int4*)(label + (size_t)b * HW);
    float tv = 0.0f;
    #pragma unroll 2
    for (int i = 0; i < HW / (256 * 4); ++i) {
        int4 l = lrow[i * 256 + t];
        if (l.x != IGNORE_L) tv += 1.0f;
        if ((unsigned)l.x < NUM_CLASS) { float v = smw[l.x * 64 + lane]; smw[l.x * 64 + lane] = v + 1.0f; }
        if (l.y != IGNORE_L) tv += 1.0f;
        if ((unsigned)l.y < NUM_CLASS) { float v = smw[l.y * 64 + lane]; smw[l.y * 64 + lane] = v + 1.0f; }
        if (l.z != IGNORE_L) tv += 1.0f;
        if ((unsigned)l.z < NUM_CLASS) { float v = smw[l.z * 64 + lane]; smw[l.z * 64 + lane] = v + 1.0f; }
        if (l.w != IGNORE_L) tv += 1.0f;
        if ((unsigned)l.w < NUM_CLASS) { float v = smw[l.w * 64 + lane]; smw[l.w * 64 + lane] = v + 1.0f; }
    }
    __syncthreads();

    for (int c = wave; c < NUM_CLASS; c += 4) {
        const int idx = c * 64 + lane;
        float v = sm[0][idx] + sm[1][idx] + sm[2][idx] + sm[3][idx];
        v = waveReduce(v);
        if (lane == 0) counts[b * NUM_CLASS + c] = v;
    }

    tv = waveReduce(tv);
    if (lane == 0) red[wave] = tv;
    __syncthreads();
    if (t == 0) total_parts[b] = red[0] + red[1] + red[2] + red[3];
}

// ---------------------------------------------------------------------------
// Kernel 3: finalize (1 block, 512 threads).
//  0: sum ss_parts[4096].
//  A: centers, intra correction  corr = sum cen*(n*cen - 2S); batch-mean cm.
//  C: per-class norms of cm.   D: 21x21 cosine sim -> inter loss.
//  out[0] = (ss + corr)/(total+eps); out[1] = sum relu(sim-.5)/(21+eps).
// ---------------------------------------------------------------------------
__global__ __launch_bounds__(512) void car_finalize_kernel(
    const float* __restrict__ class_sum, const float* __restrict__ counts,
    const float* __restrict__ ss_parts, const float* __restrict__ total_parts,
    float* __restrict__ out)
{
    __shared__ float cm[NUM_CLASS * DCH];
    __shared__ float norms[NUM_CLASS];
    __shared__ float redC[8];
    __shared__ float redS[8];
    __shared__ float redB[8];
    const int t = threadIdx.x;
    const int lane = t & 63;
    const int wave = t >> 6;

    float ssp = 0.0f;
    #pragma unroll
    for (int i = 0; i < NROWS / 512; ++i) ssp += ss_parts[i * 512 + t];

    float corr = 0.0f;
    for (int p = t; p < NUM_CLASS * DCH; p += 512) {
        const int c = p >> 9;
        float s = 0.0f;
        #pragma unroll
        for (int b = 0; b < BATCH; ++b) {
            float S = class_sum[(size_t)b * NUM_CLASS * DCH + p];
            float n = counts[b * NUM_CLASS + c];
            float cen = S / (n + EPSF);
            corr += cen * (n * cen - 2.0f * S);
            s += cen;
        }
        cm[p] = s * (1.0f / BATCH);
    }
    corr = waveReduce(corr);
    ssp  = waveReduce(ssp);
    if (lane == 0) { redC[wave] = corr; redS[wave] = ssp; }
    __syncthreads();

    for (int c = wave; c < NUM_CLASS; c += 8) {
        float s = 0.0f;
        #pragma unroll
        for (int k = 0; k < DCH / 64; ++k) {
            float v = cm[c * DCH + k * 64 + lane];
            s += v * v;
        }
        s = waveReduce(s);
        if (lane == 0) norms[c] = fmaxf(sqrtf(s), 1e-12f);
    }
    __syncthreads();

    float interAcc = 0.0f;
    for (int p = wave; p < NUM_CLASS * NUM_CLASS; p += 8) {
        const int c1 = p / NUM_CLASS;
        const int c2 = p % NUM_CLASS;
        if (c1 == c2) continue;
        float s = 0.0f;
        #pragma unroll
        for (int k = 0; k < DCH / 64; ++k)
            s += cm[c1 * DCH + k * 64 + lane] * cm[c2 * DCH + k * 64 + lane];
        s = waveReduce(s);
        if (lane == 0) {
            float sim = s / (norms[c1] * norms[c2]);
            interAcc += fmaxf(sim - 0.5f, 0.0f);
        }
    }
    if (lane == 0) redB[wave] = interAcc;
    __syncthreads();

    if (t == 0) {
        float corrT = 0.0f, interT = 0.0f, ssT = 0.0f, tot = 0.0f;
        #pragma unroll
        for (int w = 0; w < 8; ++w) { corrT += redC[w]; interT += redB[w]; ssT += redS[w]; }
        #pragma unroll
        for (int b = 0; b < BATCH; ++b) tot += total_parts[b];
        out[0] = (ssT + corrT) / (tot + EPSF);
        out[1] = interT / ((float)NUM_CLASS + EPSF);
    }
}

extern "C" void kernel_launch(void* const* d_in, const int* in_sizes, int n_in,
                              void* d_out, int out_size, void* d_ws, size_t ws_size,
                              hipStream_t stream) {
    const float* features = (const float*)d_in[0];
    const int*   label    = (const int*)d_in[1];
    float* out = (float*)d_out;

    // ws layout (floats):
    //   [0 .. 4096)          ss_parts
    //   [4096 .. 4104)       total_parts
    //   [4104 .. 4272)       counts (8*21)
    //   [4352 .. 90368)      class_sum[8][21][512]
    float* ws          = (float*)d_ws;
    float* ss_parts    = ws + 0;
    float* total_parts = ws + 4096;
    float* counts      = ws + 4104;
    float* class_sum   = ws + 4352;

    car_counts_kernel<<<BATCH, 256, 0, stream>>>(label, counts, total_parts);
    car_scatter_kernel<<<NROWS, 256, 0, stream>>>(features, label, class_sum, ss_parts);
    car_finalize_kernel<<<1, 512, 0, stream>>>(class_sum, counts, ss_parts, total_parts, out);
}

// Round 5
// 85.655 us; speedup vs baseline: 5.3744x; 1.2438x over previous
//
#include <hip/hip_runtime.h>
#include <hip/hip_bf16.h>

#define NUM_CLASS 21
#define NCLS_PAD 22            // class 21 = dump slot for invalid labels
#define IGNORE_L 255
#define EPSF 1e-6f
// Problem dims (fixed by setup_inputs): B=8, D=512, H=W=128 -> HW=16384
#define BATCH 8
#define DCH 512
#define HW 16384
#define NROWS (BATCH * DCH)   // 4096 scatter blocks

__device__ __forceinline__ float waveReduce(float v) {
    #pragma unroll
    for (int m = 1; m < 64; m <<= 1) v += __shfl_xor(v, m, 64);
    return v;
}

// Batched LDS RMW for one float4/int4. Slot rotation (lane + 16*pos) & 63
// makes the 4 addresses mutually distinct BY CONSTRUCTION (same class or
// not), so the source order R,R,R,R / add*4 / W,W,W,W is safe and costs one
// lgkmcnt stall per 4 elements instead of 4. Invalid labels -> dump class 21
// with +0 (branchless). Rotation is absorbed by the final sum over slots.
__device__ __forceinline__ void rmw4(float* __restrict__ smw, int lane,
                                     float4 f, int4 l, float scale_is_one,
                                     float& ss) {
    const int cx = ((unsigned)l.x < NUM_CLASS) ? l.x : NUM_CLASS;
    const int cy = ((unsigned)l.y < NUM_CLASS) ? l.y : NUM_CLASS;
    const int cz = ((unsigned)l.z < NUM_CLASS) ? l.z : NUM_CLASS;
    const int cw = ((unsigned)l.w < NUM_CLASS) ? l.w : NUM_CLASS;
    const int ax = cx * 64 + ( lane        & 63);
    const int ay = cy * 64 + ((lane + 16) & 63);
    const int az = cz * 64 + ((lane + 32) & 63);
    const int aw = cw * 64 + ((lane + 48) & 63);
    const float gx = (cx < NUM_CLASS) ? (scale_is_one != 0.0f ? 1.0f : f.x) : 0.0f;
    const float gy = (cy < NUM_CLASS) ? (scale_is_one != 0.0f ? 1.0f : f.y) : 0.0f;
    const float gz = (cz < NUM_CLASS) ? (scale_is_one != 0.0f ? 1.0f : f.z) : 0.0f;
    const float gw = (cw < NUM_CLASS) ? (scale_is_one != 0.0f ? 1.0f : f.w) : 0.0f;
    const float vx = smw[ax];
    const float vy = smw[ay];
    const float vz = smw[az];
    const float vw = smw[aw];
    smw[ax] = vx + gx;
    smw[ay] = vy + gy;
    smw[az] = vz + gz;
    smw[aw] = vw + gw;
    ss += (l.x != IGNORE_L) ? f.x * f.x : 0.0f;
    ss += (l.y != IGNORE_L) ? f.y * f.y : 0.0f;
    ss += (l.z != IGNORE_L) ? f.z * f.z : 0.0f;
    ss += (l.w != IGNORE_L) ? f.w * f.w : 0.0f;
}

// ---------------------------------------------------------------------------
// Fused kernel: blocks [0,8) do per-batch counts; blocks [8, 8+NROWS) do the
// per-(b,d) row segmented class sums + sum-of-squares partials.
// Per-wave private LDS copies (no atomics); 2-deep software-pipelined global
// loads so DRAM stays saturated across the LDS RMW phase.
// ---------------------------------------------------------------------------
__global__ __launch_bounds__(256) void car_fused_kernel(
    const float* __restrict__ features, const int* __restrict__ label,
    float* __restrict__ class_sum, float* __restrict__ ss_parts,
    float* __restrict__ counts, float* __restrict__ total_parts)
{
    __shared__ float sm[4][NCLS_PAD * 64];
    __shared__ float red[4];
    const int t = threadIdx.x;
    const int lane = t & 63;
    const int wave = t >> 6;

    float* __restrict__ smw = &sm[wave][0];
    for (int i = lane; i < NCLS_PAD * 64; i += 64) smw[i] = 0.0f;
    __syncthreads();

    if (blockIdx.x < BATCH) {
        // ---- counts path ----
        const int b = blockIdx.x;
        const int4* __restrict__ lrow = (const int4*)(label + (size_t)b * HW);
        const float4 fz = {0.f, 0.f, 0.f, 0.f};
        float tv = 0.0f;
        #pragma unroll 2
        for (int i = 0; i < 16; ++i) {
            int4 l = lrow[i * 256 + t];
            float dummy = 0.0f;
            rmw4(smw, lane, fz, l, 1.0f, dummy);
            tv += (l.x != IGNORE_L) ? 1.0f : 0.0f;
            tv += (l.y != IGNORE_L) ? 1.0f : 0.0f;
            tv += (l.z != IGNORE_L) ? 1.0f : 0.0f;
            tv += (l.w != IGNORE_L) ? 1.0f : 0.0f;
        }
        __syncthreads();
        for (int c = wave; c < NUM_CLASS; c += 4) {
            const int idx = c * 64 + lane;
            float v = sm[0][idx] + sm[1][idx] + sm[2][idx] + sm[3][idx];
            v = waveReduce(v);
            if (lane == 0) counts[b * NUM_CLASS + c] = v;
        }
        tv = waveReduce(tv);
        if (lane == 0) red[wave] = tv;
        __syncthreads();
        if (t == 0) total_parts[b] = red[0] + red[1] + red[2] + red[3];
        return;
    }

    // ---- scatter path ----
    const int row = blockIdx.x - BATCH;   // b*512 + d
    const int b = row >> 9;
    const int d = row & 511;

    const float4* __restrict__ frow = (const float4*)(features + (size_t)row * HW);
    const int4*  __restrict__ lrow = (const int4*)(label + (size_t)b * HW);

    // 2-deep pipelined main loop: prefetch iterations i+2, i+3 while
    // processing i, i+1 so global loads stay in flight across LDS RMW stalls.
    float4 fa = frow[t];
    float4 fb = frow[256 + t];
    int4   la = lrow[t];
    int4   lb = lrow[256 + t];
    float ss = 0.0f;

    #pragma unroll 1
    for (int i = 0; i < 16; i += 2) {
        float4 fc, fd;
        int4   lc, ld;
        if (i + 2 < 16) {
            fc = frow[(i + 2) * 256 + t];
            lc = lrow[(i + 2) * 256 + t];
            fd = frow[(i + 3) * 256 + t];
            ld = lrow[(i + 3) * 256 + t];
        }
        rmw4(smw, lane, fa, la, 0.0f, ss);
        rmw4(smw, lane, fb, lb, 0.0f, ss);
        fa = fc; la = lc;
        fb = fd; lb = ld;
    }
    __syncthreads();

    // Merge 4 wave-copies, reduce 64 slots per class (rotation-invariant).
    float* __restrict__ out_row = class_sum + (size_t)b * NUM_CLASS * DCH + d;
    for (int c = wave; c < NUM_CLASS; c += 4) {
        const int idx = c * 64 + lane;
        float v = sm[0][idx] + sm[1][idx] + sm[2][idx] + sm[3][idx];
        v = waveReduce(v);
        if (lane == 0) out_row[(size_t)c * DCH] = v;
    }

    ss = waveReduce(ss);
    if (lane == 0) red[wave] = ss;
    __syncthreads();
    if (t == 0) ss_parts[row] = red[0] + red[1] + red[2] + red[3];
}

// ---------------------------------------------------------------------------
// Finalize (1 block, 512 threads).
//  0: sum ss_parts[4096].
//  A: centers, intra correction  corr = sum cen*(n*cen - 2S); batch-mean cm.
//  C: per-class norms of cm.   D: 21x21 cosine sim -> inter loss.
//  out[0] = (ss + corr)/(total+eps); out[1] = sum relu(sim-.5)/(21+eps).
// ---------------------------------------------------------------------------
__global__ __launch_bounds__(512) void car_finalize_kernel(
    const float* __restrict__ class_sum, const float* __restrict__ counts,
    const float* __restrict__ ss_parts, const float* __restrict__ total_parts,
    float* __restrict__ out)
{
    __shared__ float cm[NUM_CLASS * DCH];
    __shared__ float norms[NUM_CLASS];
    __shared__ float redC[8];
    __shared__ float redS[8];
    __shared__ float redB[8];
    const int t = threadIdx.x;
    const int lane = t & 63;
    const int wave = t >> 6;

    float ssp = 0.0f;
    #pragma unroll
    for (int i = 0; i < NROWS / 512; ++i) ssp += ss_parts[i * 512 + t];

    float corr = 0.0f;
    for (int p = t; p < NUM_CLASS * DCH; p += 512) {
        const int c = p >> 9;
        float s = 0.0f;
        #pragma unroll
        for (int b = 0; b < BATCH; ++b) {
            float S = class_sum[(size_t)b * NUM_CLASS * DCH + p];
            float n = counts[b * NUM_CLASS + c];
            float cen = S / (n + EPSF);
            corr += cen * (n * cen - 2.0f * S);
            s += cen;
        }
        cm[p] = s * (1.0f / BATCH);
    }
    corr = waveReduce(corr);
    ssp  = waveReduce(ssp);
    if (lane == 0) { redC[wave] = corr; redS[wave] = ssp; }
    __syncthreads();

    for (int c = wave; c < NUM_CLASS; c += 8) {
        float s = 0.0f;
        #pragma unroll
        for (int k = 0; k < DCH / 64; ++k) {
            float v = cm[c * DCH + k * 64 + lane];
            s += v * v;
        }
        s = waveReduce(s);
        if (lane == 0) norms[c] = fmaxf(sqrtf(s), 1e-12f);
    }
    __syncthreads();

    float interAcc = 0.0f;
    for (int p = wave; p < NUM_CLASS * NUM_CLASS; p += 8) {
        const int c1 = p / NUM_CLASS;
        const int c2 = p % NUM_CLASS;
        if (c1 == c2) continue;
        float s = 0.0f;
        #pragma unroll
        for (int k = 0; k < DCH / 64; ++k)
            s += cm[c1 * DCH + k * 64 + lane] * cm[c2 * DCH + k * 64 + lane];
        s = waveReduce(s);
        if (lane == 0) {
            float sim = s / (norms[c1] * norms[c2]);
            interAcc += fmaxf(sim - 0.5f, 0.0f);
        }
    }
    if (lane == 0) redB[wave] = interAcc;
    __syncthreads();

    if (t == 0) {
        float corrT = 0.0f, interT = 0.0f, ssT = 0.0f, tot = 0.0f;
        #pragma unroll
        for (int w = 0; w < 8; ++w) { corrT += redC[w]; interT += redB[w]; ssT += redS[w]; }
        #pragma unroll
        for (int b = 0; b < BATCH; ++b) tot += total_parts[b];
        out[0] = (ssT + corrT) / (tot + EPSF);
        out[1] = interT / ((float)NUM_CLASS + EPSF);
    }
}

extern "C" void kernel_launch(void* const* d_in, const int* in_sizes, int n_in,
                              void* d_out, int out_size, void* d_ws, size_t ws_size,
                              hipStream_t stream) {
    const float* features = (const float*)d_in[0];
    const int*   label    = (const int*)d_in[1];
    float* out = (float*)d_out;

    // ws layout (floats):
    //   [0 .. 4096)          ss_parts
    //   [4096 .. 4104)       total_parts
    //   [4104 .. 4272)       counts (8*21)
    //   [4352 .. 90368)      class_sum[8][21][512]
    float* ws          = (float*)d_ws;
    float* ss_parts    = ws + 0;
    float* total_parts = ws + 4096;
    float* counts      = ws + 4104;
    float* class_sum   = ws + 4352;

    car_fused_kernel<<<NROWS + BATCH, 256, 0, stream>>>(
        features, label, class_sum, ss_parts, counts, total_parts);
    car_finalize_kernel<<<1, 512, 0, stream>>>(class_sum, counts, ss_parts, total_parts, out);
}

// Round 6
// 83.323 us; speedup vs baseline: 5.5248x; 1.0280x over previous
//
#include <hip/hip_runtime.h>
#include <hip/hip_bf16.h>

#define NUM_CLASS 21
#define IGNORE_L 255
#define EPSF 1e-6f
// Problem dims (fixed by setup_inputs): B=8, D=512, H=W=128 -> HW=16384
#define BATCH 8
#define DCH 512
#define HW 16384
#define NROWS (BATCH * DCH)   // 4096 scatter blocks

__device__ __forceinline__ float waveReduce(float v) {
    #pragma unroll
    for (int m = 1; m < 64; m <<= 1) v += __shfl_xor(v, m, 64);
    return v;
}

// Batched LDS RMW for one float4/int4. Slot rotation s0..s3 = (lane+16k)&63
// makes the 4 addresses mutually distinct BY CONSTRUCTION, so R,R,R,R /
// add*4 / W,W,W,W is safe (one lgkmcnt stall per 4 elements). Invalid labels
// clamp to class 0 with a gated +0 (branchless, no pad class needed).
// ss += g*f gives f*f for valid elements, 0 otherwise (labels are 0..20|255).
__device__ __forceinline__ void rmw4(float* __restrict__ smw,
                                     int s0, int s1, int s2, int s3,
                                     float4 f, int4 l, float& ss) {
    const bool bx = (unsigned)l.x < NUM_CLASS;
    const bool by = (unsigned)l.y < NUM_CLASS;
    const bool bz = (unsigned)l.z < NUM_CLASS;
    const bool bw = (unsigned)l.w < NUM_CLASS;
    const int ax = (bx ? l.x : 0) * 64 + s0;
    const int ay = (by ? l.y : 0) * 64 + s1;
    const int az = (bz ? l.z : 0) * 64 + s2;
    const int aw = (bw ? l.w : 0) * 64 + s3;
    const float gx = bx ? f.x : 0.0f;
    const float gy = by ? f.y : 0.0f;
    const float gz = bz ? f.z : 0.0f;
    const float gw = bw ? f.w : 0.0f;
    const float tx = smw[ax];
    const float ty = smw[ay];
    const float tz = smw[az];
    const float tw = smw[aw];
    smw[ax] = tx + gx;
    smw[ay] = ty + gy;
    smw[az] = tz + gz;
    smw[aw] = tw + gw;
    ss = fmaf(gx, f.x, ss);
    ss = fmaf(gy, f.y, ss);
    ss = fmaf(gz, f.z, ss);
    ss = fmaf(gw, f.w, ss);
}

// ---------------------------------------------------------------------------
// Fused kernel: blocks [0,8) do per-batch counts; blocks [8, 8+NROWS) do the
// per-(b,d) row segmented class sums + sum-of-squares partials.
// Per-wave private LDS copies (no atomics; gfx950 ds_add_f32 is ~lane-serial).
// 4-step prefetch ring: each float4/int4 pair is consumed ~4 rmw4 bodies
// (~800-1000 cyc) after its load issues, covering ~900 cyc HBM latency.
// ---------------------------------------------------------------------------
__global__ __launch_bounds__(256) void car_fused_kernel(
    const float* __restrict__ features, const int* __restrict__ label,
    float* __restrict__ class_sum, float* __restrict__ ss_parts,
    float* __restrict__ counts, float* __restrict__ total_parts)
{
    __shared__ float sm[4][NUM_CLASS * 64];
    __shared__ float red[4];
    const int t = threadIdx.x;
    const int lane = t & 63;
    const int wave = t >> 6;
    const int s0 = lane;
    const int s1 = (lane + 16) & 63;
    const int s2 = (lane + 32) & 63;
    const int s3 = (lane + 48) & 63;

    float* __restrict__ smw = &sm[wave][0];
    #pragma unroll
    for (int i = lane; i < NUM_CLASS * 64; i += 64) smw[i] = 0.0f;
    // no sync needed: each wave touches only its own copy until the merge

    if (blockIdx.x < BATCH) {
        // ---- counts path: same machinery with f = (1,1,1,1); ss == count ----
        const int b = blockIdx.x;
        const int4* __restrict__ lrow = (const int4*)(label + (size_t)b * HW);
        const float4 f1 = {1.f, 1.f, 1.f, 1.f};
        float tv = 0.0f;
        #pragma unroll 4
        for (int i = 0; i < 16; ++i) {
            int4 l = lrow[i * 256 + t];
            rmw4(smw, s0, s1, s2, s3, f1, l, tv);
        }
        __syncthreads();
        for (int c = wave; c < NUM_CLASS; c += 4) {
            const int idx = c * 64 + lane;
            float v = sm[0][idx] + sm[1][idx] + sm[2][idx] + sm[3][idx];
            v = waveReduce(v);
            if (lane == 0) counts[b * NUM_CLASS + c] = v;
        }
        tv = waveReduce(tv);
        if (lane == 0) red[wave] = tv;
        __syncthreads();
        if (t == 0) total_parts[b] = red[0] + red[1] + red[2] + red[3];
        return;
    }

    // ---- scatter path ----
    const int row = blockIdx.x - BATCH;   // b*512 + d
    const int b = row >> 9;
    const int d = row & 511;

    const float4* __restrict__ frow = (const float4*)(features + (size_t)row * HW);
    const int4*  __restrict__ lrow = (const int4*)(label + (size_t)b * HW);

    // 4-step prefetch ring.
    float4 F0 = frow[0 * 256 + t], F1 = frow[1 * 256 + t];
    float4 F2 = frow[2 * 256 + t], F3 = frow[3 * 256 + t];
    int4   L0 = lrow[0 * 256 + t], L1 = lrow[1 * 256 + t];
    int4   L2 = lrow[2 * 256 + t], L3 = lrow[3 * 256 + t];
    float ss = 0.0f;

    #pragma unroll 1
    for (int i = 0; i < 12; i += 4) {
        rmw4(smw, s0, s1, s2, s3, F0, L0, ss);
        F0 = frow[(i + 4) * 256 + t]; L0 = lrow[(i + 4) * 256 + t];
        rmw4(smw, s0, s1, s2, s3, F1, L1, ss);
        F1 = frow[(i + 5) * 256 + t]; L1 = lrow[(i + 5) * 256 + t];
        rmw4(smw, s0, s1, s2, s3, F2, L2, ss);
        F2 = frow[(i + 6) * 256 + t]; L2 = lrow[(i + 6) * 256 + t];
        rmw4(smw, s0, s1, s2, s3, F3, L3, ss);
        F3 = frow[(i + 7) * 256 + t]; L3 = lrow[(i + 7) * 256 + t];
    }
    rmw4(smw, s0, s1, s2, s3, F0, L0, ss);
    rmw4(smw, s0, s1, s2, s3, F1, L1, ss);
    rmw4(smw, s0, s1, s2, s3, F2, L2, ss);
    rmw4(smw, s0, s1, s2, s3, F3, L3, ss);
    __syncthreads();

    // Merge 4 wave-copies, reduce 64 slots per class (rotation-invariant).
    float* __restrict__ out_row = class_sum + (size_t)b * NUM_CLASS * DCH + d;
    for (int c = wave; c < NUM_CLASS; c += 4) {
        const int idx = c * 64 + lane;
        float v = sm[0][idx] + sm[1][idx] + sm[2][idx] + sm[3][idx];
        v = waveReduce(v);
        if (lane == 0) out_row[(size_t)c * DCH] = v;
    }

    ss = waveReduce(ss);
    if (lane == 0) red[wave] = ss;
    __syncthreads();
    if (t == 0) ss_parts[row] = red[0] + red[1] + red[2] + red[3];
}

// ---------------------------------------------------------------------------
// Finalize (1 block, 512 threads).
//  0: sum ss_parts[4096].
//  A: centers, intra correction  corr = sum cen*(n*cen - 2S); batch-mean cm.
//  C: per-class norms of cm.   D: 21x21 cosine sim -> inter loss.
//  out[0] = (ss + corr)/(total+eps); out[1] = sum relu(sim-.5)/(21+eps).
// ---------------------------------------------------------------------------
__global__ __launch_bounds__(512) void car_finalize_kernel(
    const float* __restrict__ class_sum, const float* __restrict__ counts,
    const float* __restrict__ ss_parts, const float* __restrict__ total_parts,
    float* __restrict__ out)
{
    __shared__ float cm[NUM_CLASS * DCH];
    __shared__ float norms[NUM_CLASS];
    __shared__ float redC[8];
    __shared__ float redS[8];
    __shared__ float redB[8];
    const int t = threadIdx.x;
    const int lane = t & 63;
    const int wave = t >> 6;

    float ssp = 0.0f;
    #pragma unroll
    for (int i = 0; i < NROWS / 512; ++i) ssp += ss_parts[i * 512 + t];

    float corr = 0.0f;
    for (int p = t; p < NUM_CLASS * DCH; p += 512) {
        const int c = p >> 9;
        float s = 0.0f;
        #pragma unroll
        for (int b = 0; b < BATCH; ++b) {
            float S = class_sum[(size_t)b * NUM_CLASS * DCH + p];
            float n = counts[b * NUM_CLASS + c];
            float cen = S / (n + EPSF);
            corr += cen * (n * cen - 2.0f * S);
            s += cen;
        }
        cm[p] = s * (1.0f / BATCH);
    }
    corr = waveReduce(corr);
    ssp  = waveReduce(ssp);
    if (lane == 0) { redC[wave] = corr; redS[wave] = ssp; }
    __syncthreads();

    for (int c = wave; c < NUM_CLASS; c += 8) {
        float s = 0.0f;
        #pragma unroll
        for (int k = 0; k < DCH / 64; ++k) {
            float v = cm[c * DCH + k * 64 + lane];
            s += v * v;
        }
        s = waveReduce(s);
        if (lane == 0) norms[c] = fmaxf(sqrtf(s), 1e-12f);
    }
    __syncthreads();

    float interAcc = 0.0f;
    for (int p = wave; p < NUM_CLASS * NUM_CLASS; p += 8) {
        const int c1 = p / NUM_CLASS;
        const int c2 = p % NUM_CLASS;
        if (c1 == c2) continue;
        float s = 0.0f;
        #pragma unroll
        for (int k = 0; k < DCH / 64; ++k)
            s += cm[c1 * DCH + k * 64 + lane] * cm[c2 * DCH + k * 64 + lane];
        s = waveReduce(s);
        if (lane == 0) {
            float sim = s / (norms[c1] * norms[c2]);
            interAcc += fmaxf(sim - 0.5f, 0.0f);
        }
    }
    if (lane == 0) redB[wave] = interAcc;
    __syncthreads();

    if (t == 0) {
        float corrT = 0.0f, interT = 0.0f, ssT = 0.0f, tot = 0.0f;
        #pragma unroll
        for (int w = 0; w < 8; ++w) { corrT += redC[w]; interT += redB[w]; ssT += redS[w]; }
        #pragma unroll
        for (int b = 0; b < BATCH; ++b) tot += total_parts[b];
        out[0] = (ssT + corrT) / (tot + EPSF);
        out[1] = interT / ((float)NUM_CLASS + EPSF);
    }
}

extern "C" void kernel_launch(void* const* d_in, const int* in_sizes, int n_in,
                              void* d_out, int out_size, void* d_ws, size_t ws_size,
                              hipStream_t stream) {
    const float* features = (const float*)d_in[0];
    const int*   label    = (const int*)d_in[1];
    float* out = (float*)d_out;

    // ws layout (floats):
    //   [0 .. 4096)          ss_parts
    //   [4096 .. 4104)       total_parts
    //   [4104 .. 4272)       counts (8*21)
    //   [4352 .. 90368)      class_sum[8][21][512]
    float* ws          = (float*)d_ws;
    float* ss_parts    = ws + 0;
    float* total_parts = ws + 4096;
    float* counts      = ws + 4104;
    float* class_sum   = ws + 4352;

    car_fused_kernel<<<NROWS + BATCH, 256, 0, stream>>>(
        features, label, class_sum, ss_parts, counts, total_parts);
    car_finalize_kernel<<<1, 512, 0, stream>>>(class_sum, counts, ss_parts, total_parts, out);
}